// Round 9
// baseline (374.409 us; speedup 1.0000x reference)
//
#include <hip/hip_runtime.h>
#include <cstdint>

typedef __bf16 bf16x8 __attribute__((ext_vector_type(8)));
typedef float floatx4 __attribute__((ext_vector_type(4)));
typedef float floatx16 __attribute__((ext_vector_type(16)));
typedef unsigned short u16;
typedef unsigned int u32;

#define SCALE2 0.1275434297677098f   // (1/sqrt(128)) * log2(e)
#define CLIP2  144.26950408889634f   // 100 * log2(e)
#define DEFER  8.0f                  // defer-max threshold (log2 domain): p <= 2^8

__device__ __forceinline__ u16 f2bf(float f) {
  union { float f; u32 i; } v; v.f = f;
  u32 r = v.i + 0x7fffu + ((v.i >> 16) & 1u);
  return (u16)(r >> 16);
}

// packed f32x2 -> bf16x2 (RNE), dst.lo = bf16(lo), dst.hi = bf16(hi)
__device__ __forceinline__ u32 cvtpk(float lo, float hi) {
  u32 r;
  asm("v_cvt_pk_bf16_f32 %0, %1, %2" : "=v"(r) : "v"(lo), "v"(hi));
  return r;
}

// async global->LDS 16B: per-lane global address, wave-uniform LDS base + lane*16
__device__ __forceinline__ void gll16(const void* g, void* l) {
  __builtin_amdgcn_global_load_lds(
      (const __attribute__((address_space(1))) u32*)g,
      (__attribute__((address_space(3))) u32*)l, 16, 0, 0);
}

// counted-vmcnt barrier (T4): drains only the oldest outstanding loads,
// leaving newer prefetches in flight across the barrier.
#define VMBAR(N)                                                   \
  do {                                                             \
    asm volatile("s_waitcnt vmcnt(" #N ")" ::: "memory");          \
    __builtin_amdgcn_s_barrier();                                  \
  } while (0)

// ---------------- fp32 -> bf16 elementwise convert ---------------------------
__global__ __launch_bounds__(256) void convert_bf16(
    const float* __restrict__ src, u16* __restrict__ dst, int n4) {
  int i = blockIdx.x * 256 + threadIdx.x;
  if (i >= n4) return;
  float4 v = ((const float4*)src)[i];
  ushort4 o;
  o.x = f2bf(v.x); o.y = f2bf(v.y); o.z = f2bf(v.z); o.w = f2bf(v.w);
  ((ushort4*)dst)[i] = o;
}

// ---------------- transpose (fp32 in, bf16 out), both weight jobs fused ------
__global__ __launch_bounds__(256) void transpose_all(
    const float* __restrict__ Wq, const float* __restrict__ Wk,
    const float* __restrict__ Wv, const float* __restrict__ Wo,
    u16* __restrict__ Wqkv_t, u16* __restrict__ Wot) {
  __shared__ u16 tile[32][33];
  const int k0 = blockIdx.x * 32, ny = blockIdx.y;
  const float* src; int ld, nb, n0; u16* dst;
  if (ny < 80) {
    n0 = ny * 32; dst = Wqkv_t;
    if (n0 < 2048)      { src = Wq; ld = 2048; nb = n0; }
    else if (n0 < 2304) { src = Wk; ld = 256;  nb = n0 - 2048; }
    else                { src = Wv; ld = 256;  nb = n0 - 2304; }
  } else {
    n0 = (ny - 80) * 32; dst = Wot; src = Wo; ld = 2048; nb = n0;
  }
  const int tx = threadIdx.x, ty = threadIdx.y;
#pragma unroll
  for (int i = 0; i < 4; i++) {
    int k = ty + i * 8;
    tile[k][tx] = f2bf(src[(size_t)(k0 + k) * ld + nb + tx]);
  }
  __syncthreads();
#pragma unroll
  for (int i = 0; i < 4; i++) {
    int n = ty + i * 8;
    dst[(size_t)(n0 + n) * 2048 + k0 + tx] = tile[tx][n];
  }
}

// ---------------- GEMM: C[M,N] = A[M,K] @ Bt[N,K]^T (+bias) ------------------
// 128x128 tile, BK=32. v2 (this round): T4 counted-vmcnt 3-buffer ring (the
// R7-attn schedule, correctness-validated on-chip) + frag-major conflict-free
// LDS (the attn kernel's verified pattern).
//   ring: issue(0,b0),issue(1,b1); per iter: vmcnt(4); s_barrier; issue(t+2,
//   buf[(t-1)%3]); compute(t, buf[t%3]).  Drained loads have 2 compute phases
//   (~700cyc) + 3-blocks/CU of cover vs the old 1-phase __syncthreads drain.
//   Hazards: WAR issue(t+2)->buf last read by compute(t-1) one barrier ago;
//   RAW vmcnt(4) leaves exactly tile t+1 in flight (4 loads/wave/tile).
//   frag-major LDS: frag f (16 rows x 32 K) stored lane-major: byte L*16 holds
//   row f*16+(L&15), k=(L>>4)*8..+8. gload_lds writes base+L*16 linearly, so
//   the per-lane GLOBAL src is pre-permuted (m173). Every ds_read_b128 is
//   frag_base+L*16 -> contiguous 1KB, 0 bank conflicts (was 8-way at [128][32]).
template <int EPI, int NWG>
__global__ __launch_bounds__(256) void gemm_bt(
    const u16* __restrict__ A, const u16* __restrict__ Bt,
    const float* __restrict__ bias0, const float* __restrict__ bias1,
    const float* __restrict__ bias2,
    u16* __restrict__ out0, u16* __restrict__ out1, u16* __restrict__ out2,
    float* __restrict__ outf,
    int M, int N, int K) {
  __shared__ u16 As[3][4096];   // 3 bufs x 8 frags x 512 u16 (1KB) = 24 KB
  __shared__ u16 Bs[3][4096];   // 24 KB  (total 48 KB -> 3 blocks/CU)
  const int tid  = threadIdx.x;
  const int w    = tid >> 6, L = tid & 63, ln = L & 15, quad = L >> 4;
  // XCD swizzle (bijective, NWG % 8 == 0)
  const int lin  = blockIdx.x + gridDim.x * blockIdx.y;
  const int swz  = (lin & 7) * (NWG >> 3) + (lin >> 3);
  const int bx   = swz % gridDim.x, by = swz / gridDim.x;
  const int m0   = by * 128, n0 = bx * 128;
  const int mw   = (w & 1) * 64, nw = (w >> 1) * 64;
  // staging: wave w stages A frags {2w,2w+1} and B frags {2w,2w+1};
  // per-lane global src: row = frag*16 + (L&15), k = (L>>4)*8  (pre-permuted)
  const int hk8 = quad * 8;
  const u16* gA[2];
  const u16* gB[2];
#pragma unroll
  for (int j = 0; j < 2; j++) {
    gA[j] = &A [(size_t)(m0 + (2 * w + j) * 16 + ln) * K + hk8];
    gB[j] = &Bt[(size_t)(n0 + (2 * w + j) * 16 + ln) * K + hk8];
  }
  floatx4 acc[4][4] = {};
  const int nk = K >> 5;

  auto issue = [&](int i, int ib) {
    const size_t kt = (size_t)i * 32;
#pragma unroll
    for (int j = 0; j < 2; j++) {
      gll16(gA[j] + kt, &As[ib][(2 * w + j) << 9]);
      gll16(gB[j] + kt, &Bs[ib][(2 * w + j) << 9]);
    }
  };

  issue(0, 0);
  issue(1, 1);
  int cb = 0;
  for (int t = 0; t < nk - 1; t++) {
    VMBAR(4);                          // drains loads(t); tile t+1 stays in flight
    int ib = cb - 1; if (ib < 0) ib = 2;   // buffer for tile t+2 = (cb+2)%3
    if (t + 2 < nk) issue(t + 2, ib);
    bf16x8 af[4], bf[4];
#pragma unroll
    for (int mb = 0; mb < 4; mb++)
      af[mb] = *(const bf16x8*)&As[cb][(((w & 1) * 4 + mb) << 9) + (L << 3)];
#pragma unroll
    for (int nb = 0; nb < 4; nb++)
      bf[nb] = *(const bf16x8*)&Bs[cb][(((w >> 1) * 4 + nb) << 9) + (L << 3)];
#pragma unroll
    for (int mb = 0; mb < 4; mb++)
#pragma unroll
      for (int nb = 0; nb < 4; nb++)
        acc[mb][nb] = __builtin_amdgcn_mfma_f32_16x16x32_bf16(af[mb], bf[nb], acc[mb][nb], 0, 0, 0);
    cb = (cb == 2) ? 0 : cb + 1;
  }
  // last tile
  VMBAR(0);
  {
    bf16x8 af[4], bf[4];
#pragma unroll
    for (int mb = 0; mb < 4; mb++)
      af[mb] = *(const bf16x8*)&As[cb][(((w & 1) * 4 + mb) << 9) + (L << 3)];
#pragma unroll
    for (int nb = 0; nb < 4; nb++)
      bf[nb] = *(const bf16x8*)&Bs[cb][(((w >> 1) * 4 + nb) << 9) + (L << 3)];
#pragma unroll
    for (int mb = 0; mb < 4; mb++)
#pragma unroll
      for (int nb = 0; nb < 4; nb++)
        acc[mb][nb] = __builtin_amdgcn_mfma_f32_16x16x32_bf16(af[mb], bf[nb], acc[mb][nb], 0, 0, 0);
  }

#pragma unroll
  for (int mb = 0; mb < 4; mb++) {
#pragma unroll
    for (int nb = 0; nb < 4; nb++) {
#pragma unroll
      for (int r = 0; r < 4; r++) {
        const int m = m0 + mw + mb * 16 + quad * 4 + r;
        const int n = n0 + nw + nb * 16 + ln;
        float v = acc[mb][nb][r];
        if constexpr (EPI == 0) {
          if (n < 2048) {            // Q: bf16, pre-scaled by SCALE2
            v = (v + bias0[n]) * SCALE2;
            out0[(size_t)m * 2048 + n] = f2bf(v);
          } else if (n < 2304) {     // K: bf16 [4096][256]
            const int j = n - 2048;
            v += bias1[j];
            out1[(size_t)m * 256 + j] = f2bf(v);
          } else {                   // V transposed: Vt[(b*2+hk)*128+d][t]
            const int j = n - 2304;  // j = hk*128 + d
            v += bias2[j];
            const int b = m >> 11, t = m & 2047;
            out2[((size_t)(b * 256 + j)) * 2048 + t] = f2bf(v);
          }
        } else {
          v += bias0[n];
          outf[(size_t)m * (size_t)N + n] = v;
        }
      }
    }
  }
}

// ---------------- flash attention (S^T, 32x32 MFMA, KVBLK=64, T15) -----------
// CHAMPION (90.5 us, round 8). Unchanged.
__global__ __launch_bounds__(256, 2) void attn_kernel(
    const u16* __restrict__ Q, const u16* __restrict__ K,
    const u16* __restrict__ Vt, u16* __restrict__ O) {
  __shared__ u16 Ksh[2][16 * 512];   // 32 KB: 16 frags of 1KB (frag-major)
  __shared__ u16 Vsh[2][16 * 512];   // 32 KB
  const int tid = threadIdx.x;
  const int w = tid >> 6, L = tid & 63;
  const int ln = L & 31, hf = L >> 5;
  const int qt = blockIdx.x, h = blockIdx.y, b = blockIdx.z;
  const int hk = h >> 3;  // G = 8
  const size_t qrow0 = (size_t)b * 2048 + qt * 128 + w * 32;

  const u16* Kbase = K + (size_t)b * 2048 * 256 + hk * 128;
  const u16* Vbase = Vt + (size_t)(b * 2 + hk) * 128 * 2048;

  const u16* gK[4];
  const u16* gV[4];
#pragma unroll
  for (int j = 0; j < 4; j++) {
    const int fK = 4 * w + j, mb = fK >> 3, kc = fK & 7;
    gK[j] = Kbase + (size_t)(mb * 32 + ln) * 256 + kc * 16 + hf * 8;
    const int fV = 4 * w + j, db = fV >> 2, ks = fV & 3;
    gV[j] = Vbase + (size_t)(db * 32 + ln) * 2048 + ks * 16 + hf * 8;
  }

  bf16x8 qf[8];
#pragma unroll
  for (int kc = 0; kc < 8; kc++)
    qf[kc] = *(const bf16x8*)&Q[(qrow0 + ln) * 2048 + h * 128 + kc * 16 + hf * 8];

  floatx16 oT[4] = {};               // O^T: col=q=lane&31, row d=32db+(r&3)+8(r>>2)+4hf
  float mrow = -1e30f, lrow = 0.f;   // per-lane (qrow = ln), shared with lane^32

  auto issue = [&](int tile, int bufi) {
#pragma unroll
    for (int j = 0; j < 4; j++) {
      gll16(gK[j] + (size_t)tile * 64 * 256, &Ksh[bufi][(4 * w + j) * 512]);
      gll16(gV[j] + (size_t)tile * 64,       &Vsh[bufi][(4 * w + j) * 512]);
    }
  };

  auto qkt = [&](floatx16 (&sf)[2], const u16* kb) {
#pragma unroll
    for (int r = 0; r < 16; r++) { sf[0][r] = 0.f; sf[1][r] = 0.f; }
#pragma unroll
    for (int kc = 0; kc < 8; kc++) {
#pragma unroll
      for (int mb = 0; mb < 2; mb++) {
        bf16x8 kf = *(const bf16x8*)&kb[(mb * 8 + kc) * 512 + L * 8];
        sf[mb] = __builtin_amdgcn_mfma_f32_32x32x16_bf16(kf, qf[kc], sf[mb], 0, 0, 0);
      }
    }
  };

  auto softmax = [&](floatx16 (&sf)[2]) {
#pragma unroll
    for (int mb = 0; mb < 2; mb++)
#pragma unroll
      for (int r = 0; r < 16; r++)
        sf[mb][r] = __builtin_amdgcn_fmed3f(sf[mb][r], -CLIP2, CLIP2);
    float t16[16];
#pragma unroll
    for (int r = 0; r < 16; r++) t16[r] = fmaxf(sf[0][r], sf[1][r]);
#pragma unroll
    for (int d = 8; d >= 1; d >>= 1)
#pragma unroll
      for (int r = 0; r < d; r++) t16[r] = fmaxf(t16[r], t16[r + d]);
    const float mx = fmaxf(t16[0], __shfl_xor(t16[0], 32));
    const bool need = __ballot(mx > mrow + DEFER) != 0;   // wave-uniform
    float mn = mrow, alpha = 1.f;
    if (need) {
      mn = fmaxf(mrow, mx);
      alpha = __builtin_amdgcn_exp2f(mrow - mn);
      mrow = mn;
    }
#pragma unroll
    for (int mb = 0; mb < 2; mb++)
#pragma unroll
      for (int r = 0; r < 16; r++)
        sf[mb][r] = __builtin_amdgcn_exp2f(sf[mb][r] - mn);
    float s16[16];
#pragma unroll
    for (int r = 0; r < 16; r++) s16[r] = sf[0][r] + sf[1][r];
#pragma unroll
    for (int d = 8; d >= 1; d >>= 1)
#pragma unroll
      for (int r = 0; r < d; r++) s16[r] += s16[r + d];
    const float s = s16[0] + __shfl_xor(s16[0], 32);
    if (need) {
      lrow = lrow * alpha + s;
#pragma unroll
      for (int db = 0; db < 4; db++)
#pragma unroll
        for (int r = 0; r < 16; r++) oT[db][r] *= alpha;
    } else {
      lrow += s;
    }
  };

  auto pv = [&](floatx16 (&sf)[2], const u16* vb) {
#pragma unroll
    for (int ks = 0; ks < 4; ks++) {
      const int mb = ks >> 1, s8 = (ks & 1) * 8;
      u32 cA0 = cvtpk(sf[mb][s8 + 0], sf[mb][s8 + 1]);
      u32 cA1 = cvtpk(sf[mb][s8 + 2], sf[mb][s8 + 3]);
      u32 cB0 = cvtpk(sf[mb][s8 + 4], sf[mb][s8 + 5]);
      u32 cB1 = cvtpk(sf[mb][s8 + 6], sf[mb][s8 + 7]);
      asm("v_permlane32_swap_b32 %0, %1" : "+v"(cA0), "+v"(cB0));
      asm("v_permlane32_swap_b32 %0, %1" : "+v"(cA1), "+v"(cB1));
      union { u32 u[4]; bf16x8 v; } pb;
      pb.u[0] = cA0; pb.u[1] = cA1; pb.u[2] = cB0; pb.u[3] = cB1;
#pragma unroll
      for (int db = 0; db < 4; db++) {
        bf16x8 vf = *(const bf16x8*)&vb[(db * 4 + ks) * 512 + L * 8];
        oT[db] = __builtin_amdgcn_mfma_f32_32x32x16_bf16(vf, pb.v, oT[db], 0, 0, 0);
      }
    }
  };

  floatx16 sfA[2], sfB[2];

  // prologue
  issue(0, 0);
  __syncthreads();                      // drain tile 0
  issue(1, 1);
  qkt(sfA, &Ksh[0][0]);                 // tile 0 scores (loads(1) in flight)

  for (int t = 0; t < 32; t += 2) {
    // ---- tile t (sfA, buf0) ----
    softmax(sfA);
    __syncthreads();                    // drains loads(t+1) -> buf1
    __builtin_amdgcn_s_setprio(1);
    qkt(sfB, &Ksh[1][0]);               // tile t+1 (t <= 30, always valid)
    pv(sfA, &Vsh[0][0]);                // tile t
    __builtin_amdgcn_s_setprio(0);
    __syncthreads();                    // all waves done reading buf0
    if (t + 2 < 32) issue(t + 2, 0);
    // ---- tile t+1 (sfB, buf1) ----
    softmax(sfB);
    __syncthreads();                    // drains loads(t+2) -> buf0
    __builtin_amdgcn_s_setprio(1);
    if (t + 2 < 32) qkt(sfA, &Ksh[0][0]);  // tile t+2
    pv(sfB, &Vsh[1][0]);                // tile t+1
    __builtin_amdgcn_s_setprio(0);
    __syncthreads();                    // all waves done reading buf1
    if (t + 3 < 32) issue(t + 3, 1);
  }

  // ---- epilogue: O[qrow=ln][h*128 + 32db + 8g + 4hf + d4], 8B stores
  const float inv = 1.f / lrow;
  u16* orow = O + (qrow0 + ln) * 2048 + h * 128;
#pragma unroll
  for (int db = 0; db < 4; db++) {
#pragma unroll
    for (int g = 0; g < 4; g++) {
      uint2 st;
      st.x = cvtpk(oT[db][g * 4 + 0] * inv, oT[db][g * 4 + 1] * inv);
      st.y = cvtpk(oT[db][g * 4 + 2] * inv, oT[db][g * 4 + 3] * inv);
      *(uint2*)&orow[db * 32 + g * 8 + hf * 4] = st;
    }
  }
}

extern "C" void kernel_launch(void* const* d_in, const int* in_sizes, int n_in,
                              void* d_out, int out_size, void* d_ws, size_t ws_size,
                              hipStream_t stream) {
  const float* x  = (const float*)d_in[0];
  const float* Wq = (const float*)d_in[1];
  const float* bq = (const float*)d_in[2];
  const float* Wk = (const float*)d_in[3];
  const float* bk = (const float*)d_in[4];
  const float* Wv = (const float*)d_in[5];
  const float* bv = (const float*)d_in[6];
  const float* Wo = (const float*)d_in[7];
  const float* bo = (const float*)d_in[8];
  float* out = (float*)d_out;

  // Workspace layout (bytes). xb is dead after the QKV GEMM, so Ob aliases it.
  char* ws = (char*)d_ws;
  u16* xb     = (u16*)(ws);                      // 4096*2048*2 = 16777216
  u16* Ob     = (u16*)(ws);                      // aliases xb (attn runs after gemm1)
  u16* Wqkv_t = (u16*)(ws + 16777216);           // 2560*2048*2 = 10485760
  u16* Wot    = (u16*)(ws + 27262976);           // 2048*2048*2 =  8388608
  u16* Qb     = (u16*)(ws + 35651584);           // 4096*2048*2 = 16777216
  u16* Kb     = (u16*)(ws + 52428800);           // 4096*256*2  =  2097152
  u16* Vtb    = (u16*)(ws + 54525952);           // 512*2048*2  =  2097152
  (void)in_sizes; (void)n_in; (void)out_size; (void)ws_size;

  convert_bf16<<<8192, 256, 0, stream>>>(x, xb, 2097152);

  transpose_all<<<dim3(64, 144), dim3(32, 8), 0, stream>>>(
      Wq, Wk, Wv, Wo, Wqkv_t, Wot);

  gemm_bt<0, 640><<<dim3(20, 32), 256, 0, stream>>>(
      xb, Wqkv_t, bq, bk, bv, Qb, Kb, Vtb, nullptr, 4096, 2560, 2048);

  attn_kernel<<<dim3(16, 16, 2), 256, 0, stream>>>(Qb, Kb, Vtb, Ob);

  gemm_bt<1, 512><<<dim3(16, 32), 256, 0, stream>>>(
      Ob, Wot, bo, nullptr, nullptr, nullptr, nullptr, nullptr, out, 4096, 2048, 2048);
}

// Round 10
// 320.919 us; speedup vs baseline: 1.1667x; 1.1667x over previous
//
#include <hip/hip_runtime.h>
#include <cstdint>

typedef __bf16 bf16x8 __attribute__((ext_vector_type(8)));
typedef float floatx4 __attribute__((ext_vector_type(4)));
typedef float floatx16 __attribute__((ext_vector_type(16)));
typedef unsigned short u16;
typedef unsigned int u32;

#define SCALE2 0.1275434297677098f   // (1/sqrt(128)) * log2(e)
#define CLIP2  144.26950408889634f   // 100 * log2(e)
#define DEFER  8.0f                  // defer-max threshold (log2 domain): p <= 2^8

__device__ __forceinline__ u16 f2bf(float f) {
  union { float f; u32 i; } v; v.f = f;
  u32 r = v.i + 0x7fffu + ((v.i >> 16) & 1u);
  return (u16)(r >> 16);
}

// packed f32x2 -> bf16x2 (RNE), dst.lo = bf16(lo), dst.hi = bf16(hi)
__device__ __forceinline__ u32 cvtpk(float lo, float hi) {
  u32 r;
  asm("v_cvt_pk_bf16_f32 %0, %1, %2" : "=v"(r) : "v"(lo), "v"(hi));
  return r;
}

// async global->LDS 16B: per-lane global address, wave-uniform LDS base + lane*16
__device__ __forceinline__ void gll16(const void* g, void* l) {
  __builtin_amdgcn_global_load_lds(
      (const __attribute__((address_space(1))) u32*)g,
      (__attribute__((address_space(3))) u32*)l, 16, 0, 0);
}

// counted-vmcnt barrier (T4): drains only the oldest outstanding loads,
// leaving newer prefetches in flight across the barrier.
#define VMBAR(N)                                                   \
  do {                                                             \
    asm volatile("s_waitcnt vmcnt(" #N ")" ::: "memory");          \
    __builtin_amdgcn_s_barrier();                                  \
  } while (0)

// ---------------- fp32 -> bf16 elementwise convert ---------------------------
__global__ __launch_bounds__(256) void convert_bf16(
    const float* __restrict__ src, u16* __restrict__ dst, int n4) {
  int i = blockIdx.x * 256 + threadIdx.x;
  if (i >= n4) return;
  float4 v = ((const float4*)src)[i];
  ushort4 o;
  o.x = f2bf(v.x); o.y = f2bf(v.y); o.z = f2bf(v.z); o.w = f2bf(v.w);
  ((ushort4*)dst)[i] = o;
}

// ---------------- transpose (fp32 in, bf16 out), both weight jobs fused ------
__global__ __launch_bounds__(256) void transpose_all(
    const float* __restrict__ Wq, const float* __restrict__ Wk,
    const float* __restrict__ Wv, const float* __restrict__ Wo,
    u16* __restrict__ Wqkv_t, u16* __restrict__ Wot) {
  __shared__ u16 tile[32][33];
  const int k0 = blockIdx.x * 32, ny = blockIdx.y;
  const float* src; int ld, nb, n0; u16* dst;
  if (ny < 80) {
    n0 = ny * 32; dst = Wqkv_t;
    if (n0 < 2048)      { src = Wq; ld = 2048; nb = n0; }
    else if (n0 < 2304) { src = Wk; ld = 256;  nb = n0 - 2048; }
    else                { src = Wv; ld = 256;  nb = n0 - 2304; }
  } else {
    n0 = (ny - 80) * 32; dst = Wot; src = Wo; ld = 2048; nb = n0;
  }
  const int tx = threadIdx.x, ty = threadIdx.y;
#pragma unroll
  for (int i = 0; i < 4; i++) {
    int k = ty + i * 8;
    tile[k][tx] = f2bf(src[(size_t)(k0 + k) * ld + nb + tx]);
  }
  __syncthreads();
#pragma unroll
  for (int i = 0; i < 4; i++) {
    int n = ty + i * 8;
    dst[(size_t)(n0 + n) * 2048 + k0 + tx] = tile[tx][n];
  }
}

// ---------------- GEMM: C[M,N] = A[M,K] @ Bt[N,K]^T (+bias) ------------------
// 128x128 tile, BK=32. Round-10: T4 3-buffer counted-vmcnt ring ISOLATED --
// R8's verified coalesced staging (lane quads read 64B contiguous) and
// [128][32] LDS layout are kept verbatim; only the sync schedule changes.
// (R9 bundled the ring with frag-major staging whose permuted per-lane global
// src destroyed adjacent-lane coalescing: 16x64B -> 64x16B requests/instr,
// 4x L2 request rate -> all-pipes-idle stall, +25%. Detangled here.)
//   ring: issue(0,b0),issue(1,b1); per iter t: vmcnt(4); s_barrier;
//   issue(t+2, buf[(t+2)%3]); compute(t, buf[t%3]).  Peeled last iter vmcnt(0).
//   Drained loads have 2 compute phases of cover vs __syncthreads' 1.
//   Hazards: WAR issue(t+2)->buf last read by compute(t-1), one barrier ago;
//   RAW vmcnt(4) drains exactly tile t (4 loads/wave/tile, in-order retire).
template <int EPI, int NWG>
__global__ __launch_bounds__(256) void gemm_bt(
    const u16* __restrict__ A, const u16* __restrict__ Bt,
    const float* __restrict__ bias0, const float* __restrict__ bias1,
    const float* __restrict__ bias2,
    u16* __restrict__ out0, u16* __restrict__ out1, u16* __restrict__ out2,
    float* __restrict__ outf,
    int M, int N, int K) {
  __shared__ u16 As[3][128][32];   // 24 KB
  __shared__ u16 Bs[3][128][32];   // 24 KB (48 total -> 3 blocks/CU, grid avg 2.5)
  const int tid  = threadIdx.x;
  const int w    = tid >> 6, L = tid & 63, ln = L & 15, quad = L >> 4;
  // XCD swizzle (bijective, NWG % 8 == 0)
  const int lin  = blockIdx.x + gridDim.x * blockIdx.y;
  const int swz  = (lin & 7) * (NWG >> 3) + (lin >> 3);
  const int bx   = swz % gridDim.x, by = swz / gridDim.x;
  const int m0   = by * 128, n0 = bx * 128;
  const int mw   = (w & 1) * 64, nw = (w >> 1) * 64;
  const int sr = w * 32 + (L >> 2), sc = (L & 3) * 8;   // coalesced: 4 lanes = 64B
  const u16* ga = &A [(size_t)(m0 + sr) * K + sc];
  const u16* gb = &Bt[(size_t)(n0 + sr) * K + sc];
  floatx4 acc[4][4] = {};
  const int nk = K >> 5;

  auto issue = [&](int i, int ib) {
    const size_t kt = (size_t)i << 5;
    gll16(ga + kt,                  &As[ib][w * 32][0]);
    gll16(ga + (size_t)16 * K + kt, &As[ib][w * 32 + 16][0]);
    gll16(gb + kt,                  &Bs[ib][w * 32][0]);
    gll16(gb + (size_t)16 * K + kt, &Bs[ib][w * 32 + 16][0]);
  };
  auto compute = [&](int cb) {
    bf16x8 af[4], bf[4];
#pragma unroll
    for (int mb = 0; mb < 4; mb++) af[mb] = *(const bf16x8*)&As[cb][mw + mb * 16 + ln][quad * 8];
#pragma unroll
    for (int nb = 0; nb < 4; nb++) bf[nb] = *(const bf16x8*)&Bs[cb][nw + nb * 16 + ln][quad * 8];
#pragma unroll
    for (int mb = 0; mb < 4; mb++)
#pragma unroll
      for (int nb = 0; nb < 4; nb++)
        acc[mb][nb] = __builtin_amdgcn_mfma_f32_16x16x32_bf16(af[mb], bf[nb], acc[mb][nb], 0, 0, 0);
  };

  issue(0, 0);
  issue(1, 1);
  int cb = 0;
  for (int t = 0; t < nk - 1; t++) {
    VMBAR(4);                              // drains tile t; t+1 stays in flight
    int ib = cb - 1; if (ib < 0) ib = 2;   // (cb+2)%3
    if (t + 2 < nk) issue(t + 2, ib);
    compute(cb);
    cb = (cb == 2) ? 0 : cb + 1;
  }
  VMBAR(0);                                // drains the final tile
  compute(cb);

#pragma unroll
  for (int mb = 0; mb < 4; mb++) {
#pragma unroll
    for (int nb = 0; nb < 4; nb++) {
#pragma unroll
      for (int r = 0; r < 4; r++) {
        const int m = m0 + mw + mb * 16 + quad * 4 + r;
        const int n = n0 + nw + nb * 16 + ln;
        float v = acc[mb][nb][r];
        if constexpr (EPI == 0) {
          if (n < 2048) {            // Q: bf16, pre-scaled by SCALE2
            v = (v + bias0[n]) * SCALE2;
            out0[(size_t)m * 2048 + n] = f2bf(v);
          } else if (n < 2304) {     // K: bf16 [4096][256]
            const int j = n - 2048;
            v += bias1[j];
            out1[(size_t)m * 256 + j] = f2bf(v);
          } else {                   // V transposed: Vt[(b*2+hk)*128+d][t]
            const int j = n - 2304;  // j = hk*128 + d
            v += bias2[j];
            const int b = m >> 11, t = m & 2047;
            out2[((size_t)(b * 256 + j)) * 2048 + t] = f2bf(v);
          }
        } else {
          v += bias0[n];
          outf[(size_t)m * (size_t)N + n] = v;
        }
      }
    }
  }
}

// ---------------- flash attention (S^T, 32x32 MFMA, KVBLK=64, T15) -----------
// CHAMPION (90.5 us, round 8). Unchanged.
__global__ __launch_bounds__(256, 2) void attn_kernel(
    const u16* __restrict__ Q, const u16* __restrict__ K,
    const u16* __restrict__ Vt, u16* __restrict__ O) {
  __shared__ u16 Ksh[2][16 * 512];   // 32 KB: 16 frags of 1KB (frag-major)
  __shared__ u16 Vsh[2][16 * 512];   // 32 KB
  const int tid = threadIdx.x;
  const int w = tid >> 6, L = tid & 63;
  const int ln = L & 31, hf = L >> 5;
  const int qt = blockIdx.x, h = blockIdx.y, b = blockIdx.z;
  const int hk = h >> 3;  // G = 8
  const size_t qrow0 = (size_t)b * 2048 + qt * 128 + w * 32;

  const u16* Kbase = K + (size_t)b * 2048 * 256 + hk * 128;
  const u16* Vbase = Vt + (size_t)(b * 2 + hk) * 128 * 2048;

  const u16* gK[4];
  const u16* gV[4];
#pragma unroll
  for (int j = 0; j < 4; j++) {
    const int fK = 4 * w + j, mb = fK >> 3, kc = fK & 7;
    gK[j] = Kbase + (size_t)(mb * 32 + ln) * 256 + kc * 16 + hf * 8;
    const int fV = 4 * w + j, db = fV >> 2, ks = fV & 3;
    gV[j] = Vbase + (size_t)(db * 32 + ln) * 2048 + ks * 16 + hf * 8;
  }

  bf16x8 qf[8];
#pragma unroll
  for (int kc = 0; kc < 8; kc++)
    qf[kc] = *(const bf16x8*)&Q[(qrow0 + ln) * 2048 + h * 128 + kc * 16 + hf * 8];

  floatx16 oT[4] = {};               // O^T: col=q=lane&31, row d=32db+(r&3)+8(r>>2)+4hf
  float mrow = -1e30f, lrow = 0.f;   // per-lane (qrow = ln), shared with lane^32

  auto issue = [&](int tile, int bufi) {
#pragma unroll
    for (int j = 0; j < 4; j++) {
      gll16(gK[j] + (size_t)tile * 64 * 256, &Ksh[bufi][(4 * w + j) * 512]);
      gll16(gV[j] + (size_t)tile * 64,       &Vsh[bufi][(4 * w + j) * 512]);
    }
  };

  auto qkt = [&](floatx16 (&sf)[2], const u16* kb) {
#pragma unroll
    for (int r = 0; r < 16; r++) { sf[0][r] = 0.f; sf[1][r] = 0.f; }
#pragma unroll
    for (int kc = 0; kc < 8; kc++) {
#pragma unroll
      for (int mb = 0; mb < 2; mb++) {
        bf16x8 kf = *(const bf16x8*)&kb[(mb * 8 + kc) * 512 + L * 8];
        sf[mb] = __builtin_amdgcn_mfma_f32_32x32x16_bf16(kf, qf[kc], sf[mb], 0, 0, 0);
      }
    }
  };

  auto softmax = [&](floatx16 (&sf)[2]) {
#pragma unroll
    for (int mb = 0; mb < 2; mb++)
#pragma unroll
      for (int r = 0; r < 16; r++)
        sf[mb][r] = __builtin_amdgcn_fmed3f(sf[mb][r], -CLIP2, CLIP2);
    float t16[16];
#pragma unroll
    for (int r = 0; r < 16; r++) t16[r] = fmaxf(sf[0][r], sf[1][r]);
#pragma unroll
    for (int d = 8; d >= 1; d >>= 1)
#pragma unroll
      for (int r = 0; r < d; r++) t16[r] = fmaxf(t16[r], t16[r + d]);
    const float mx = fmaxf(t16[0], __shfl_xor(t16[0], 32));
    const bool need = __ballot(mx > mrow + DEFER) != 0;   // wave-uniform
    float mn = mrow, alpha = 1.f;
    if (need) {
      mn = fmaxf(mrow, mx);
      alpha = __builtin_amdgcn_exp2f(mrow - mn);
      mrow = mn;
    }
#pragma unroll
    for (int mb = 0; mb < 2; mb++)
#pragma unroll
      for (int r = 0; r < 16; r++)
        sf[mb][r] = __builtin_amdgcn_exp2f(sf[mb][r] - mn);
    float s16[16];
#pragma unroll
    for (int r = 0; r < 16; r++) s16[r] = sf[0][r] + sf[1][r];
#pragma unroll
    for (int d = 8; d >= 1; d >>= 1)
#pragma unroll
      for (int r = 0; r < d; r++) s16[r] += s16[r + d];
    const float s = s16[0] + __shfl_xor(s16[0], 32);
    if (need) {
      lrow = lrow * alpha + s;
#pragma unroll
      for (int db = 0; db < 4; db++)
#pragma unroll
        for (int r = 0; r < 16; r++) oT[db][r] *= alpha;
    } else {
      lrow += s;
    }
  };

  auto pv = [&](floatx16 (&sf)[2], const u16* vb) {
#pragma unroll
    for (int ks = 0; ks < 4; ks++) {
      const int mb = ks >> 1, s8 = (ks & 1) * 8;
      u32 cA0 = cvtpk(sf[mb][s8 + 0], sf[mb][s8 + 1]);
      u32 cA1 = cvtpk(sf[mb][s8 + 2], sf[mb][s8 + 3]);
      u32 cB0 = cvtpk(sf[mb][s8 + 4], sf[mb][s8 + 5]);
      u32 cB1 = cvtpk(sf[mb][s8 + 6], sf[mb][s8 + 7]);
      asm("v_permlane32_swap_b32 %0, %1" : "+v"(cA0), "+v"(cB0));
      asm("v_permlane32_swap_b32 %0, %1" : "+v"(cA1), "+v"(cB1));
      union { u32 u[4]; bf16x8 v; } pb;
      pb.u[0] = cA0; pb.u[1] = cA1; pb.u[2] = cB0; pb.u[3] = cB1;
#pragma unroll
      for (int db = 0; db < 4; db++) {
        bf16x8 vf = *(const bf16x8*)&vb[(db * 4 + ks) * 512 + L * 8];
        oT[db] = __builtin_amdgcn_mfma_f32_32x32x16_bf16(vf, pb.v, oT[db], 0, 0, 0);
      }
    }
  };

  floatx16 sfA[2], sfB[2];

  // prologue
  issue(0, 0);
  __syncthreads();                      // drain tile 0
  issue(1, 1);
  qkt(sfA, &Ksh[0][0]);                 // tile 0 scores (loads(1) in flight)

  for (int t = 0; t < 32; t += 2) {
    // ---- tile t (sfA, buf0) ----
    softmax(sfA);
    __syncthreads();                    // drains loads(t+1) -> buf1
    __builtin_amdgcn_s_setprio(1);
    qkt(sfB, &Ksh[1][0]);               // tile t+1 (t <= 30, always valid)
    pv(sfA, &Vsh[0][0]);                // tile t
    __builtin_amdgcn_s_setprio(0);
    __syncthreads();                    // all waves done reading buf0
    if (t + 2 < 32) issue(t + 2, 0);
    // ---- tile t+1 (sfB, buf1) ----
    softmax(sfB);
    __syncthreads();                    // drains loads(t+2) -> buf0
    __builtin_amdgcn_s_setprio(1);
    if (t + 2 < 32) qkt(sfA, &Ksh[0][0]);  // tile t+2
    pv(sfB, &Vsh[1][0]);                // tile t+1
    __builtin_amdgcn_s_setprio(0);
    __syncthreads();                    // all waves done reading buf1
    if (t + 3 < 32) issue(t + 3, 1);
  }

  // ---- epilogue: O[qrow=ln][h*128 + 32db + 8g + 4hf + d4], 8B stores
  const float inv = 1.f / lrow;
  u16* orow = O + (qrow0 + ln) * 2048 + h * 128;
#pragma unroll
  for (int db = 0; db < 4; db++) {
#pragma unroll
    for (int g = 0; g < 4; g++) {
      uint2 st;
      st.x = cvtpk(oT[db][g * 4 + 0] * inv, oT[db][g * 4 + 1] * inv);
      st.y = cvtpk(oT[db][g * 4 + 2] * inv, oT[db][g * 4 + 3] * inv);
      *(uint2*)&orow[db * 32 + g * 8 + hf * 4] = st;
    }
  }
}

extern "C" void kernel_launch(void* const* d_in, const int* in_sizes, int n_in,
                              void* d_out, int out_size, void* d_ws, size_t ws_size,
                              hipStream_t stream) {
  const float* x  = (const float*)d_in[0];
  const float* Wq = (const float*)d_in[1];
  const float* bq = (const float*)d_in[2];
  const float* Wk = (const float*)d_in[3];
  const float* bk = (const float*)d_in[4];
  const float* Wv = (const float*)d_in[5];
  const float* bv = (const float*)d_in[6];
  const float* Wo = (const float*)d_in[7];
  const float* bo = (const float*)d_in[8];
  float* out = (float*)d_out;

  // Workspace layout (bytes). xb is dead after the QKV GEMM, so Ob aliases it.
  char* ws = (char*)d_ws;
  u16* xb     = (u16*)(ws);                      // 4096*2048*2 = 16777216
  u16* Ob     = (u16*)(ws);                      // aliases xb (attn runs after gemm1)
  u16* Wqkv_t = (u16*)(ws + 16777216);           // 2560*2048*2 = 10485760
  u16* Wot    = (u16*)(ws + 27262976);           // 2048*2048*2 =  8388608
  u16* Qb     = (u16*)(ws + 35651584);           // 4096*2048*2 = 16777216
  u16* Kb     = (u16*)(ws + 52428800);           // 4096*256*2  =  2097152
  u16* Vtb    = (u16*)(ws + 54525952);           // 512*2048*2  =  2097152
  (void)in_sizes; (void)n_in; (void)out_size; (void)ws_size;

  convert_bf16<<<8192, 256, 0, stream>>>(x, xb, 2097152);

  transpose_all<<<dim3(64, 144), dim3(32, 8), 0, stream>>>(
      Wq, Wk, Wv, Wo, Wqkv_t, Wot);

  gemm_bt<0, 640><<<dim3(20, 32), 256, 0, stream>>>(
      xb, Wqkv_t, bq, bk, bv, Qb, Kb, Vtb, nullptr, 4096, 2560, 2048);

  attn_kernel<<<dim3(16, 16, 2), 256, 0, stream>>>(Qb, Kb, Vtb, Ob);

  gemm_bt<1, 512><<<dim3(16, 32), 256, 0, stream>>>(
      Ob, Wot, bo, nullptr, nullptr, nullptr, nullptr, nullptr, out, 4096, 2048, 2048);
}